// Round 1
// baseline (937.662 us; speedup 1.0000x reference)
//
#include <hip/hip_runtime.h>

#define N_NODES 50000
#define N_EDGES 800000
#define N_GRAPHS 128
#define IN_CH 31
#define HID 64

// ---------------- CSR build ----------------

__global__ void hist_kernel(const int* __restrict__ dst, int* __restrict__ counts, int e) {
    int i = blockIdx.x * 256 + threadIdx.x;
    if (i < e) atomicAdd(&counts[dst[i]], 1);
}

__global__ void scan_blocks_kernel(const int* __restrict__ counts, int* __restrict__ row_ptr,
                                   int* __restrict__ blk, int n) {
    __shared__ int tmp[256];
    int tid = threadIdx.x;
    int i = blockIdx.x * 256 + tid;
    int v = (i < n) ? counts[i] : 0;
    tmp[tid] = v;
    __syncthreads();
    for (int off = 1; off < 256; off <<= 1) {
        int u = (tid >= off) ? tmp[tid - off] : 0;
        __syncthreads();
        tmp[tid] += u;
        __syncthreads();
    }
    if (i < n) row_ptr[i + 1] = tmp[tid];
    if (tid == 255) blk[blockIdx.x] = tmp[255];
}

__global__ void scan_partials_kernel(int* __restrict__ blk, int nb) {
    __shared__ int tmp[256];
    int tid = threadIdx.x;
    int v = (tid < nb) ? blk[tid] : 0;
    tmp[tid] = v;
    __syncthreads();
    for (int off = 1; off < 256; off <<= 1) {
        int u = (tid >= off) ? tmp[tid - off] : 0;
        __syncthreads();
        tmp[tid] += u;
        __syncthreads();
    }
    if (tid < nb) blk[tid] = tmp[tid] - v;  // exclusive prefix
}

__global__ void scan_add_kernel(int* __restrict__ row_ptr, const int* __restrict__ blk, int n) {
    int i = blockIdx.x * 256 + threadIdx.x;
    if (i < n) row_ptr[i + 1] += blk[blockIdx.x];
    if (i == 0) row_ptr[0] = 0;
}

__global__ void scatter_kernel(const int* __restrict__ src, const int* __restrict__ dst,
                               const int* __restrict__ row_ptr, int* __restrict__ counts,
                               int* __restrict__ csr_src, int e) {
    int i = blockIdx.x * 256 + threadIdx.x;
    if (i < e) {
        int dd = dst[i];
        int pos = row_ptr[dd] + atomicAdd(&counts[dd], 1);
        csr_src[pos] = src[i];
    }
}

// ---------------- fused conv layer ----------------
// One wave per node; lane = channel. Softmax-aggregation without max-subtraction
// (shift-invariant; |logits| <= ~8 so exp is fp32-safe), fused with the two
// linear transforms (LDS-staged transposed weights), instance norm (wave
// shuffle reduction), ReLU, and per-graph atomicMax readout.

template <int C_IN>
__global__ void __launch_bounds__(256) conv_kernel(
        const float* __restrict__ xin, const float* __restrict__ tptr,
        const int* __restrict__ row_ptr, const int* __restrict__ csr_src,
        const int* __restrict__ batch,
        const float* __restrict__ Wr, const float* __restrict__ br,
        const float* __restrict__ Ws,
        float* __restrict__ yout, float* __restrict__ hmax, int n) {
    __shared__ float wrt[C_IN * 64];   // wrt[c*64+k] = Wr[k*C_IN+c]
    __shared__ float wst[C_IN * 64];
    __shared__ float sa[4][64];
    __shared__ float sx[4][64];
    int tid = threadIdx.x;
    for (int idx = tid; idx < C_IN * 64; idx += 256) {
        int k = idx / C_IN, c = idx - k * C_IN;
        wrt[c * 64 + k] = Wr[idx];
        wst[c * 64 + k] = Ws[idx];
    }
    __syncthreads();

    int w = tid >> 6, l = tid & 63;
    int d = blockIdx.x * 4 + w;
    float tval = tptr[0];
    float aggr = 0.f, xr = 0.f;
    if (d < n) {
        if (l < C_IN) xr = xin[d * C_IN + l];
        int beg = row_ptr[d], end = row_ptr[d + 1];
        float den = 0.f, num = 0.f;
        for (int j = beg; j < end; ++j) {
            int s = csr_src[j];
            float v = (l < C_IN) ? xin[s * C_IN + l] : 0.f;
            float e = __expf(tval * v);
            den += e;
            num += v * e;
        }
        if (end > beg && l < C_IN) aggr = num / den;
    }
    sa[w][l] = aggr;
    sx[w][l] = xr;
    __syncthreads();

    if (d < n) {
        float acc = br[l];
        #pragma unroll
        for (int c = 0; c < C_IN; ++c) {
            acc = fmaf(sa[w][c], wrt[c * 64 + l], acc);
            acc = fmaf(sx[w][c], wst[c * 64 + l], acc);
        }
        // instance norm over the 64 channels (= 64 lanes)
        float s = acc;
        for (int off = 32; off > 0; off >>= 1) s += __shfl_xor(s, off);
        float mu = s * (1.0f / 64.0f);
        float dc = acc - mu;
        float s2 = dc * dc;
        for (int off = 32; off > 0; off >>= 1) s2 += __shfl_xor(s2, off);
        float var = s2 * (1.0f / 64.0f);
        float y = dc * rsqrtf(var + 1e-5f);
        y = fmaxf(y, 0.f);
        yout[d * 64 + l] = y;
        int g = batch[d];
        // y >= 0 and hmax zero-initialized: int-punned atomicMax is order-correct
        atomicMax((int*)&hmax[g * 64 + l], __float_as_int(y));
    }
}

// ---------------- MLP head ----------------

__global__ void mlp_kernel(const float* __restrict__ h,  // [3][G][64]
                           const float* __restrict__ Wl1, const float* __restrict__ bl1,
                           const float* __restrict__ Wl2, const float* __restrict__ bl2,
                           float* __restrict__ out) {
    __shared__ float hrow[192];
    __shared__ float z1[128];
    __shared__ float z2[32];
    __shared__ float snorm;
    int g = blockIdx.x, tid = threadIdx.x;  // 128 threads
    if (tid < 64) {
        hrow[tid]       = h[0 * N_GRAPHS * 64 + g * 64 + tid];
        hrow[64 + tid]  = h[1 * N_GRAPHS * 64 + g * 64 + tid];
        hrow[128 + tid] = h[2 * N_GRAPHS * 64 + g * 64 + tid];
    }
    __syncthreads();
    float acc = bl1[tid];
    #pragma unroll 8
    for (int c = 0; c < 192; ++c) acc = fmaf(hrow[c], Wl1[tid * 192 + c], acc);
    z1[tid] = fmaxf(acc, 0.f);
    __syncthreads();
    if (tid < 32) {
        float a2 = bl2[tid];
        #pragma unroll 8
        for (int c = 0; c < 128; ++c) a2 = fmaf(z1[c], Wl2[tid * 128 + c], a2);
        z2[tid] = a2;
    }
    __syncthreads();
    if (tid == 0) {
        float ss = 0.f;
        for (int i = 0; i < 32; ++i) ss += z2[i] * z2[i];
        snorm = fmaxf(sqrtf(ss), 1e-12f);
    }
    __syncthreads();
    if (tid < 32) out[g * 32 + tid] = z2[tid] / snorm;
}

// ---------------- launch ----------------

extern "C" void kernel_launch(void* const* d_in, const int* in_sizes, int n_in,
                              void* d_out, int out_size, void* d_ws, size_t ws_size,
                              hipStream_t stream) {
    const float* x   = (const float*)d_in[0];
    const int* eidx  = (const int*)d_in[1];
    const int* batch = (const int*)d_in[2];
    const float* t   = (const float*)d_in[3];
    const float* W1r = (const float*)d_in[4];
    const float* b1  = (const float*)d_in[5];
    const float* W1s = (const float*)d_in[6];
    const float* W2r = (const float*)d_in[7];
    const float* b2  = (const float*)d_in[8];
    const float* W2s = (const float*)d_in[9];
    const float* W3r = (const float*)d_in[10];
    const float* b3  = (const float*)d_in[11];
    const float* W3s = (const float*)d_in[12];
    const float* Wl1 = (const float*)d_in[13];
    const float* bl1 = (const float*)d_in[14];
    const float* Wl2 = (const float*)d_in[15];
    const float* bl2 = (const float*)d_in[16];
    float* out = (float*)d_out;

    const int nE = in_sizes[1] / 2;
    const int nN = in_sizes[2];
    const int* src = eidx;
    const int* dst = eidx + nE;

    char* ws = (char*)d_ws;
    size_t off = 0;
    auto alloc = [&](size_t bytes) {
        char* p = ws + off;
        off = (off + bytes + 255) & ~(size_t)255;
        return p;
    };
    int*   counts  = (int*)alloc((size_t)nN * 4);
    int*   row_ptr = (int*)alloc((size_t)(nN + 1) * 4);
    int*   blk     = (int*)alloc(256 * 4);
    int*   csr_src = (int*)alloc((size_t)nE * 4);
    float* yA      = (float*)alloc((size_t)nN * 64 * 4);
    float* yB      = (float*)alloc((size_t)nN * 64 * 4);
    float* h       = (float*)alloc((size_t)3 * N_GRAPHS * 64 * 4);

    const int nbE = (nE + 255) / 256;
    const int nbN = (nN + 255) / 256;

    hipMemsetAsync(counts, 0, (size_t)nN * 4, stream);
    hist_kernel<<<nbE, 256, 0, stream>>>(dst, counts, nE);
    scan_blocks_kernel<<<nbN, 256, 0, stream>>>(counts, row_ptr, blk, nN);
    scan_partials_kernel<<<1, 256, 0, stream>>>(blk, nbN);
    scan_add_kernel<<<nbN, 256, 0, stream>>>(row_ptr, blk, nN);
    hipMemsetAsync(counts, 0, (size_t)nN * 4, stream);
    scatter_kernel<<<nbE, 256, 0, stream>>>(src, dst, row_ptr, counts, csr_src, nE);
    hipMemsetAsync(h, 0, (size_t)3 * N_GRAPHS * 64 * 4, stream);

    const int nbC = (nN + 3) / 4;
    conv_kernel<IN_CH><<<nbC, 256, 0, stream>>>(x, t, row_ptr, csr_src, batch,
                                                W1r, b1, W1s, yA, h + 0 * N_GRAPHS * 64, nN);
    conv_kernel<HID><<<nbC, 256, 0, stream>>>(yA, t, row_ptr, csr_src, batch,
                                              W2r, b2, W2s, yB, h + 1 * N_GRAPHS * 64, nN);
    conv_kernel<HID><<<nbC, 256, 0, stream>>>(yB, t, row_ptr, csr_src, batch,
                                              W3r, b3, W3s, yA, h + 2 * N_GRAPHS * 64, nN);
    mlp_kernel<<<N_GRAPHS, 128, 0, stream>>>(h, Wl1, bl1, Wl2, bl2, out);
}

// Round 2
// 547.097 us; speedup vs baseline: 1.7139x; 1.7139x over previous
//
#include <hip/hip_runtime.h>

#define N_NODES 50000
#define N_EDGES 800000
#define N_GRAPHS 128
#define IN_CH 31
#define HID 64

// ---------------- CSR build ----------------

__global__ void hist_kernel(const int* __restrict__ dst, int* __restrict__ counts, int e) {
    int i = blockIdx.x * 256 + threadIdx.x;
    if (i < e) atomicAdd(&counts[dst[i]], 1);
}

__global__ void scan_blocks_kernel(const int* __restrict__ counts, int* __restrict__ row_ptr,
                                   int* __restrict__ blk, int n) {
    __shared__ int tmp[256];
    int tid = threadIdx.x;
    int i = blockIdx.x * 256 + tid;
    int v = (i < n) ? counts[i] : 0;
    tmp[tid] = v;
    __syncthreads();
    for (int off = 1; off < 256; off <<= 1) {
        int u = (tid >= off) ? tmp[tid - off] : 0;
        __syncthreads();
        tmp[tid] += u;
        __syncthreads();
    }
    if (i < n) row_ptr[i + 1] = tmp[tid];
    if (tid == 255) blk[blockIdx.x] = tmp[255];
}

__global__ void scan_partials_kernel(int* __restrict__ blk, int nb) {
    __shared__ int tmp[256];
    int tid = threadIdx.x;
    int v = (tid < nb) ? blk[tid] : 0;
    tmp[tid] = v;
    __syncthreads();
    for (int off = 1; off < 256; off <<= 1) {
        int u = (tid >= off) ? tmp[tid - off] : 0;
        __syncthreads();
        tmp[tid] += u;
        __syncthreads();
    }
    if (tid < nb) blk[tid] = tmp[tid] - v;  // exclusive prefix
}

__global__ void scan_add_kernel(int* __restrict__ row_ptr, const int* __restrict__ blk, int n) {
    int i = blockIdx.x * 256 + threadIdx.x;
    if (i < n) row_ptr[i + 1] += blk[blockIdx.x];
    if (i == 0) row_ptr[0] = 0;
}

__global__ void scatter_kernel(const int* __restrict__ src, const int* __restrict__ dst,
                               const int* __restrict__ row_ptr, int* __restrict__ counts,
                               int* __restrict__ csr_src, int e) {
    int i = blockIdx.x * 256 + threadIdx.x;
    if (i < e) {
        int dd = dst[i];
        int pos = row_ptr[dd] + atomicAdd(&counts[dd], 1);
        csr_src[pos] = src[i];
    }
}

// ---------------- fused conv layer ----------------
// One wave per node; lane = output channel. Softmax-aggregation without
// max-subtraction (shift-invariant; |t*x| <= ~8 so fp32 exp is safe).
// Edge loop: coalesced lane-load of up to 64 CSR indices, v_readlane broadcast
// (no memory dependence), 4 gathers in flight. Weights staged transposed in
// LDS with an additive swizzle (bank-conflict-free on write AND read).
// Matmul broadcast via readlane (no sa/sx LDS) -> LDS = 2*C_IN*64*4 bytes.

template <int C_IN>
__global__ void __launch_bounds__(256) conv_kernel(
        const float* __restrict__ xin, const float* __restrict__ tptr,
        const int* __restrict__ row_ptr, const int* __restrict__ csr_src,
        const int* __restrict__ batch,
        const float* __restrict__ Wr, const float* __restrict__ br,
        const float* __restrict__ Ws,
        float* __restrict__ yout, float* __restrict__ hmax, int n) {
    // wrt[c*64 + ((k+c)&63)] = Wr[k*C_IN + c]  (element (row k, col c) of Wr)
    __shared__ float wrt[C_IN * 64];
    __shared__ float wst[C_IN * 64];
    int tid = threadIdx.x;
    for (int idx = tid; idx < C_IN * 64; idx += 256) {
        int k = idx / C_IN, c = idx - k * C_IN;
        int a = c * 64 + ((k + c) & 63);
        wrt[a] = Wr[idx];
        wst[a] = Ws[idx];
    }
    __syncthreads();

    int w = tid >> 6, l = tid & 63;
    int d = blockIdx.x * 4 + w;
    if (d >= n) return;

    float tval = tptr[0];
    int loff = (l < C_IN) ? l : 0;          // clamp: lanes >= C_IN load a safe dup
    float xr = xin[d * C_IN + loff];

    int beg = row_ptr[d], end = row_ptr[d + 1];
    float den = 0.f, num = 0.f;
    for (int base = beg; base < end; base += 64) {
        int cnt = end - base;
        if (cnt > 64) cnt = 64;
        int sidx = (l < cnt) ? csr_src[base + l] : 0;   // coalesced; 0 = safe addr
        for (int j = 0; j < cnt; j += 4) {
            int s0 = __builtin_amdgcn_readlane(sidx, j);
            int s1 = __builtin_amdgcn_readlane(sidx, (j + 1) & 63);
            int s2 = __builtin_amdgcn_readlane(sidx, (j + 2) & 63);
            int s3 = __builtin_amdgcn_readlane(sidx, (j + 3) & 63);
            float v0 = xin[s0 * C_IN + loff];
            float v1 = xin[s1 * C_IN + loff];
            float v2 = xin[s2 * C_IN + loff];
            float v3 = xin[s3 * C_IN + loff];
            float e0 = __expf(tval * v0);
            float e1 = (j + 1 < cnt) ? __expf(tval * v1) : 0.f;
            float e2 = (j + 2 < cnt) ? __expf(tval * v2) : 0.f;
            float e3 = (j + 3 < cnt) ? __expf(tval * v3) : 0.f;
            den += (e0 + e1) + (e2 + e3);
            num = fmaf(v0, e0, num);
            num = fmaf(v1, e1, num);
            num = fmaf(v2, e2, num);
            num = fmaf(v3, e3, num);
        }
    }
    float aggr = (end > beg) ? num / den : 0.f;

    // acc_l = b_l + sum_c aggr_c * Wr[l][c] + x_c * Ws[l][c]
    float acc = br[l];
    #pragma unroll
    for (int c = 0; c < C_IN; ++c) {
        float av = __int_as_float(__builtin_amdgcn_readlane(__float_as_int(aggr), c));
        float xv = __int_as_float(__builtin_amdgcn_readlane(__float_as_int(xr), c));
        int a = c * 64 + ((l + c) & 63);
        acc = fmaf(av, wrt[a], acc);
        acc = fmaf(xv, wst[a], acc);
    }

    // instance norm over the 64 channels (= 64 lanes)
    float s = acc;
    for (int off = 32; off > 0; off >>= 1) s += __shfl_xor(s, off);
    float mu = s * (1.0f / 64.0f);
    float dc = acc - mu;
    float s2 = dc * dc;
    for (int off = 32; off > 0; off >>= 1) s2 += __shfl_xor(s2, off);
    float var = s2 * (1.0f / 64.0f);
    float y = dc * rsqrtf(var + 1e-5f);
    y = fmaxf(y, 0.f);
    yout[d * 64 + l] = y;
    int g = batch[d];
    // y >= 0 and hmax zero-initialized: int-punned atomicMax is order-correct
    atomicMax((int*)&hmax[g * 64 + l], __float_as_int(y));
}

// ---------------- MLP head ----------------

__global__ void mlp_kernel(const float* __restrict__ h,  // [3][G][64]
                           const float* __restrict__ Wl1, const float* __restrict__ bl1,
                           const float* __restrict__ Wl2, const float* __restrict__ bl2,
                           float* __restrict__ out) {
    __shared__ float hrow[192];
    __shared__ float z1[128];
    __shared__ float z2[32];
    __shared__ float snorm;
    int g = blockIdx.x, tid = threadIdx.x;  // 128 threads
    if (tid < 64) {
        hrow[tid]       = h[0 * N_GRAPHS * 64 + g * 64 + tid];
        hrow[64 + tid]  = h[1 * N_GRAPHS * 64 + g * 64 + tid];
        hrow[128 + tid] = h[2 * N_GRAPHS * 64 + g * 64 + tid];
    }
    __syncthreads();
    float acc = bl1[tid];
    #pragma unroll 8
    for (int c = 0; c < 192; ++c) acc = fmaf(hrow[c], Wl1[tid * 192 + c], acc);
    z1[tid] = fmaxf(acc, 0.f);
    __syncthreads();
    if (tid < 32) {
        float a2 = bl2[tid];
        #pragma unroll 8
        for (int c = 0; c < 128; ++c) a2 = fmaf(z1[c], Wl2[tid * 128 + c], a2);
        z2[tid] = a2;
    }
    __syncthreads();
    if (tid == 0) {
        float ss = 0.f;
        for (int i = 0; i < 32; ++i) ss += z2[i] * z2[i];
        snorm = fmaxf(sqrtf(ss), 1e-12f);
    }
    __syncthreads();
    if (tid < 32) out[g * 32 + tid] = z2[tid] / snorm;
}

// ---------------- launch ----------------

extern "C" void kernel_launch(void* const* d_in, const int* in_sizes, int n_in,
                              void* d_out, int out_size, void* d_ws, size_t ws_size,
                              hipStream_t stream) {
    const float* x   = (const float*)d_in[0];
    const int* eidx  = (const int*)d_in[1];
    const int* batch = (const int*)d_in[2];
    const float* t   = (const float*)d_in[3];
    const float* W1r = (const float*)d_in[4];
    const float* b1  = (const float*)d_in[5];
    const float* W1s = (const float*)d_in[6];
    const float* W2r = (const float*)d_in[7];
    const float* b2  = (const float*)d_in[8];
    const float* W2s = (const float*)d_in[9];
    const float* W3r = (const float*)d_in[10];
    const float* b3  = (const float*)d_in[11];
    const float* W3s = (const float*)d_in[12];
    const float* Wl1 = (const float*)d_in[13];
    const float* bl1 = (const float*)d_in[14];
    const float* Wl2 = (const float*)d_in[15];
    const float* bl2 = (const float*)d_in[16];
    float* out = (float*)d_out;

    const int nE = in_sizes[1] / 2;
    const int nN = in_sizes[2];
    const int* src = eidx;
    const int* dst = eidx + nE;

    char* ws = (char*)d_ws;
    size_t off = 0;
    auto alloc = [&](size_t bytes) {
        char* p = ws + off;
        off = (off + bytes + 255) & ~(size_t)255;
        return p;
    };
    int*   counts  = (int*)alloc((size_t)nN * 4);
    int*   row_ptr = (int*)alloc((size_t)(nN + 1) * 4);
    int*   blk     = (int*)alloc(256 * 4);
    int*   csr_src = (int*)alloc((size_t)nE * 4);
    float* yA      = (float*)alloc((size_t)nN * 64 * 4);
    float* yB      = (float*)alloc((size_t)nN * 64 * 4);
    float* h       = (float*)alloc((size_t)3 * N_GRAPHS * 64 * 4);

    const int nbE = (nE + 255) / 256;
    const int nbN = (nN + 255) / 256;

    hipMemsetAsync(counts, 0, (size_t)nN * 4, stream);
    hist_kernel<<<nbE, 256, 0, stream>>>(dst, counts, nE);
    scan_blocks_kernel<<<nbN, 256, 0, stream>>>(counts, row_ptr, blk, nN);
    scan_partials_kernel<<<1, 256, 0, stream>>>(blk, nbN);
    scan_add_kernel<<<nbN, 256, 0, stream>>>(row_ptr, blk, nN);
    hipMemsetAsync(counts, 0, (size_t)nN * 4, stream);
    scatter_kernel<<<nbE, 256, 0, stream>>>(src, dst, row_ptr, counts, csr_src, nE);
    hipMemsetAsync(h, 0, (size_t)3 * N_GRAPHS * 64 * 4, stream);

    const int nbC = (nN + 3) / 4;
    conv_kernel<IN_CH><<<nbC, 256, 0, stream>>>(x, t, row_ptr, csr_src, batch,
                                                W1r, b1, W1s, yA, h + 0 * N_GRAPHS * 64, nN);
    conv_kernel<HID><<<nbC, 256, 0, stream>>>(yA, t, row_ptr, csr_src, batch,
                                              W2r, b2, W2s, yB, h + 1 * N_GRAPHS * 64, nN);
    conv_kernel<HID><<<nbC, 256, 0, stream>>>(yB, t, row_ptr, csr_src, batch,
                                              W3r, b3, W3s, yA, h + 2 * N_GRAPHS * 64, nN);
    mlp_kernel<<<N_GRAPHS, 128, 0, stream>>>(h, Wl1, bl1, Wl2, bl2, out);
}

// Round 3
// 453.877 us; speedup vs baseline: 2.0659x; 1.2054x over previous
//
#include <hip/hip_runtime.h>

#define N_NODES 50000
#define N_EDGES 800000
#define N_GRAPHS 128
#define IN_CH 31
#define HID 64

// ---------------- CSR build ----------------

__global__ void hist_kernel(const int* __restrict__ dst, int* __restrict__ counts, int e) {
    int i = blockIdx.x * 256 + threadIdx.x;
    if (i < e) atomicAdd(&counts[dst[i]], 1);
}

__global__ void scan_blocks_kernel(const int* __restrict__ counts, int* __restrict__ row_ptr,
                                   int* __restrict__ blk, int n) {
    __shared__ int tmp[256];
    int tid = threadIdx.x;
    int i = blockIdx.x * 256 + tid;
    int v = (i < n) ? counts[i] : 0;
    tmp[tid] = v;
    __syncthreads();
    for (int off = 1; off < 256; off <<= 1) {
        int u = (tid >= off) ? tmp[tid - off] : 0;
        __syncthreads();
        tmp[tid] += u;
        __syncthreads();
    }
    if (i < n) row_ptr[i + 1] = tmp[tid];
    if (tid == 255) blk[blockIdx.x] = tmp[255];
}

__global__ void scan_partials_kernel(int* __restrict__ blk, int nb) {
    __shared__ int tmp[256];
    int tid = threadIdx.x;
    int v = (tid < nb) ? blk[tid] : 0;
    tmp[tid] = v;
    __syncthreads();
    for (int off = 1; off < 256; off <<= 1) {
        int u = (tid >= off) ? tmp[tid - off] : 0;
        __syncthreads();
        tmp[tid] += u;
        __syncthreads();
    }
    if (tid < nb) blk[tid] = tmp[tid] - v;  // exclusive prefix
}

__global__ void scan_add_kernel(int* __restrict__ row_ptr, const int* __restrict__ blk, int n) {
    int i = blockIdx.x * 256 + threadIdx.x;
    if (i < n) row_ptr[i + 1] += blk[blockIdx.x];
    if (i == 0) row_ptr[0] = 0;
}

__global__ void scatter_kernel(const int* __restrict__ src, const int* __restrict__ dst,
                               const int* __restrict__ row_ptr, int* __restrict__ counts,
                               int* __restrict__ csr_src, int e) {
    int i = blockIdx.x * 256 + threadIdx.x;
    if (i < e) {
        int dd = dst[i];
        int pos = row_ptr[dd] + atomicAdd(&counts[dd], 1);
        csr_src[pos] = src[i];
    }
}

// ---------------- fused conv layer ----------------
// 1024-thread blocks = 16 waves = 16 nodes/block; lane = output channel.
// 2 blocks/CU (thread cap) -> 32 waves/CU for latency hiding.
// Softmax-aggregation without max-subtraction (shift-invariant; |t*x| <= ~8).
// Edge loop: coalesced lane-load of up to 64 CSR indices, v_readlane broadcast
// (scalar addressing, no memory dep), 8 gathers in flight. Weights staged
// transposed in LDS with additive swizzle (conflict-free write AND read).

template <int C_IN>
__global__ void __launch_bounds__(1024, 8) conv_kernel(
        const float* __restrict__ xin, const float* __restrict__ tptr,
        const int* __restrict__ row_ptr, const int* __restrict__ csr_src,
        const int* __restrict__ batch,
        const float* __restrict__ Wr, const float* __restrict__ br,
        const float* __restrict__ Ws,
        float* __restrict__ yout, float* __restrict__ hmax, int n) {
    // wrt[c*64 + ((k+c)&63)] = Wr[k*C_IN + c]  (element (row k, col c) of Wr)
    __shared__ float wrt[C_IN * 64];
    __shared__ float wst[C_IN * 64];
    int tid = threadIdx.x;
    for (int idx = tid; idx < C_IN * 64; idx += 1024) {
        int k = idx / C_IN, c = idx - k * C_IN;
        int a = c * 64 + ((k + c) & 63);
        wrt[a] = Wr[idx];
        wst[a] = Ws[idx];
    }
    __syncthreads();

    int w = tid >> 6, l = tid & 63;
    int d = blockIdx.x * 16 + w;
    if (d >= n) return;

    float tval = tptr[0];
    int loff = (l < C_IN) ? l : 0;          // clamp: lanes >= C_IN load a safe dup
    float xr = xin[d * C_IN + loff];

    int beg = row_ptr[d], end = row_ptr[d + 1];
    float den = 0.f, num = 0.f;
    for (int base = beg; base < end; base += 64) {
        int cnt = end - base;
        if (cnt > 64) cnt = 64;
        int sidx = (l < cnt) ? csr_src[base + l] : 0;   // coalesced; 0 = safe addr
        int j = 0;
        for (; j + 8 <= cnt; j += 8) {
            int s0 = __builtin_amdgcn_readlane(sidx, j);
            int s1 = __builtin_amdgcn_readlane(sidx, j + 1);
            int s2 = __builtin_amdgcn_readlane(sidx, j + 2);
            int s3 = __builtin_amdgcn_readlane(sidx, j + 3);
            int s4 = __builtin_amdgcn_readlane(sidx, j + 4);
            int s5 = __builtin_amdgcn_readlane(sidx, j + 5);
            int s6 = __builtin_amdgcn_readlane(sidx, j + 6);
            int s7 = __builtin_amdgcn_readlane(sidx, j + 7);
            float v0 = xin[s0 * C_IN + loff];
            float v1 = xin[s1 * C_IN + loff];
            float v2 = xin[s2 * C_IN + loff];
            float v3 = xin[s3 * C_IN + loff];
            float v4 = xin[s4 * C_IN + loff];
            float v5 = xin[s5 * C_IN + loff];
            float v6 = xin[s6 * C_IN + loff];
            float v7 = xin[s7 * C_IN + loff];
            float e0 = __expf(tval * v0);
            float e1 = __expf(tval * v1);
            float e2 = __expf(tval * v2);
            float e3 = __expf(tval * v3);
            float e4 = __expf(tval * v4);
            float e5 = __expf(tval * v5);
            float e6 = __expf(tval * v6);
            float e7 = __expf(tval * v7);
            den += ((e0 + e1) + (e2 + e3)) + ((e4 + e5) + (e6 + e7));
            num = fmaf(v0, e0, num);
            num = fmaf(v1, e1, num);
            num = fmaf(v2, e2, num);
            num = fmaf(v3, e3, num);
            num = fmaf(v4, e4, num);
            num = fmaf(v5, e5, num);
            num = fmaf(v6, e6, num);
            num = fmaf(v7, e7, num);
        }
        for (; j < cnt; ++j) {
            int s = __builtin_amdgcn_readlane(sidx, j);
            float v = xin[s * C_IN + loff];
            float e = __expf(tval * v);
            den += e;
            num = fmaf(v, e, num);
        }
    }
    float aggr = (end > beg) ? num / den : 0.f;

    // acc_l = b_l + sum_c aggr_c * Wr[l][c] + x_c * Ws[l][c]
    float acc = br[l];
    #pragma unroll
    for (int c = 0; c < C_IN; ++c) {
        float av = __int_as_float(__builtin_amdgcn_readlane(__float_as_int(aggr), c));
        float xv = __int_as_float(__builtin_amdgcn_readlane(__float_as_int(xr), c));
        int a = c * 64 + ((l + c) & 63);
        acc = fmaf(av, wrt[a], acc);
        acc = fmaf(xv, wst[a], acc);
    }

    // instance norm over the 64 channels (= 64 lanes)
    float s = acc;
    for (int off = 32; off > 0; off >>= 1) s += __shfl_xor(s, off);
    float mu = s * (1.0f / 64.0f);
    float dc = acc - mu;
    float s2 = dc * dc;
    for (int off = 32; off > 0; off >>= 1) s2 += __shfl_xor(s2, off);
    float var = s2 * (1.0f / 64.0f);
    float y = dc * rsqrtf(var + 1e-5f);
    y = fmaxf(y, 0.f);
    yout[d * 64 + l] = y;
    int g = batch[d];
    // y >= 0 and hmax zero-initialized: int-punned atomicMax is order-correct
    atomicMax((int*)&hmax[g * 64 + l], __float_as_int(y));
}

// ---------------- MLP head ----------------

__global__ void mlp_kernel(const float* __restrict__ h,  // [3][G][64]
                           const float* __restrict__ Wl1, const float* __restrict__ bl1,
                           const float* __restrict__ Wl2, const float* __restrict__ bl2,
                           float* __restrict__ out) {
    __shared__ float hrow[192];
    __shared__ float z1[128];
    __shared__ float z2[32];
    __shared__ float snorm;
    int g = blockIdx.x, tid = threadIdx.x;  // 128 threads
    if (tid < 64) {
        hrow[tid]       = h[0 * N_GRAPHS * 64 + g * 64 + tid];
        hrow[64 + tid]  = h[1 * N_GRAPHS * 64 + g * 64 + tid];
        hrow[128 + tid] = h[2 * N_GRAPHS * 64 + g * 64 + tid];
    }
    __syncthreads();
    float acc = bl1[tid];
    #pragma unroll 8
    for (int c = 0; c < 192; ++c) acc = fmaf(hrow[c], Wl1[tid * 192 + c], acc);
    z1[tid] = fmaxf(acc, 0.f);
    __syncthreads();
    if (tid < 32) {
        float a2 = bl2[tid];
        #pragma unroll 8
        for (int c = 0; c < 128; ++c) a2 = fmaf(z1[c], Wl2[tid * 128 + c], a2);
        z2[tid] = a2;
    }
    __syncthreads();
    if (tid == 0) {
        float ss = 0.f;
        for (int i = 0; i < 32; ++i) ss += z2[i] * z2[i];
        snorm = fmaxf(sqrtf(ss), 1e-12f);
    }
    __syncthreads();
    if (tid < 32) out[g * 32 + tid] = z2[tid] / snorm;
}

// ---------------- launch ----------------

extern "C" void kernel_launch(void* const* d_in, const int* in_sizes, int n_in,
                              void* d_out, int out_size, void* d_ws, size_t ws_size,
                              hipStream_t stream) {
    const float* x   = (const float*)d_in[0];
    const int* eidx  = (const int*)d_in[1];
    const int* batch = (const int*)d_in[2];
    const float* t   = (const float*)d_in[3];
    const float* W1r = (const float*)d_in[4];
    const float* b1  = (const float*)d_in[5];
    const float* W1s = (const float*)d_in[6];
    const float* W2r = (const float*)d_in[7];
    const float* b2  = (const float*)d_in[8];
    const float* W2s = (const float*)d_in[9];
    const float* W3r = (const float*)d_in[10];
    const float* b3  = (const float*)d_in[11];
    const float* W3s = (const float*)d_in[12];
    const float* Wl1 = (const float*)d_in[13];
    const float* bl1 = (const float*)d_in[14];
    const float* Wl2 = (const float*)d_in[15];
    const float* bl2 = (const float*)d_in[16];
    float* out = (float*)d_out;

    const int nE = in_sizes[1] / 2;
    const int nN = in_sizes[2];
    const int* src = eidx;
    const int* dst = eidx + nE;

    char* ws = (char*)d_ws;
    size_t off = 0;
    auto alloc = [&](size_t bytes) {
        char* p = ws + off;
        off = (off + bytes + 255) & ~(size_t)255;
        return p;
    };
    int*   counts  = (int*)alloc((size_t)nN * 4);
    int*   row_ptr = (int*)alloc((size_t)(nN + 1) * 4);
    int*   blk     = (int*)alloc(256 * 4);
    int*   csr_src = (int*)alloc((size_t)nE * 4);
    float* yA      = (float*)alloc((size_t)nN * 64 * 4);
    float* yB      = (float*)alloc((size_t)nN * 64 * 4);
    float* h       = (float*)alloc((size_t)3 * N_GRAPHS * 64 * 4);

    const int nbE = (nE + 255) / 256;
    const int nbN = (nN + 255) / 256;

    hipMemsetAsync(counts, 0, (size_t)nN * 4, stream);
    hist_kernel<<<nbE, 256, 0, stream>>>(dst, counts, nE);
    scan_blocks_kernel<<<nbN, 256, 0, stream>>>(counts, row_ptr, blk, nN);
    scan_partials_kernel<<<1, 256, 0, stream>>>(blk, nbN);
    scan_add_kernel<<<nbN, 256, 0, stream>>>(row_ptr, blk, nN);
    hipMemsetAsync(counts, 0, (size_t)nN * 4, stream);
    scatter_kernel<<<nbE, 256, 0, stream>>>(src, dst, row_ptr, counts, csr_src, nE);
    hipMemsetAsync(h, 0, (size_t)3 * N_GRAPHS * 64 * 4, stream);

    const int nbC = (nN + 15) / 16;
    conv_kernel<IN_CH><<<nbC, 1024, 0, stream>>>(x, t, row_ptr, csr_src, batch,
                                                 W1r, b1, W1s, yA, h + 0 * N_GRAPHS * 64, nN);
    conv_kernel<HID><<<nbC, 1024, 0, stream>>>(yA, t, row_ptr, csr_src, batch,
                                               W2r, b2, W2s, yB, h + 1 * N_GRAPHS * 64, nN);
    conv_kernel<HID><<<nbC, 1024, 0, stream>>>(yB, t, row_ptr, csr_src, batch,
                                               W3r, b3, W3s, yA, h + 2 * N_GRAPHS * 64, nN);
    mlp_kernel<<<N_GRAPHS, 128, 0, stream>>>(h, Wl1, bl1, Wl2, bl2, out);
}

// Round 4
// 430.039 us; speedup vs baseline: 2.1804x; 1.0554x over previous
//
#include <hip/hip_runtime.h>

#define N_NODES 50000
#define N_EDGES 800000
#define N_GRAPHS 128
#define IN_CH 31
#define HID 64

// ---------------- CSR build ----------------

__global__ void hist_kernel(const int* __restrict__ dst, int* __restrict__ counts, int e) {
    int i = blockIdx.x * 256 + threadIdx.x;
    if (i < e) atomicAdd(&counts[dst[i]], 1);
}

__global__ void scan_blocks_kernel(const int* __restrict__ counts, int* __restrict__ row_ptr,
                                   int* __restrict__ blk, int n) {
    __shared__ int tmp[256];
    int tid = threadIdx.x;
    int i = blockIdx.x * 256 + tid;
    int v = (i < n) ? counts[i] : 0;
    tmp[tid] = v;
    __syncthreads();
    for (int off = 1; off < 256; off <<= 1) {
        int u = (tid >= off) ? tmp[tid - off] : 0;
        __syncthreads();
        tmp[tid] += u;
        __syncthreads();
    }
    if (i < n) row_ptr[i + 1] = tmp[tid];
    if (tid == 255) blk[blockIdx.x] = tmp[255];
}

__global__ void scan_partials_kernel(int* __restrict__ blk, int nb) {
    __shared__ int tmp[256];
    int tid = threadIdx.x;
    int v = (tid < nb) ? blk[tid] : 0;
    tmp[tid] = v;
    __syncthreads();
    for (int off = 1; off < 256; off <<= 1) {
        int u = (tid >= off) ? tmp[tid - off] : 0;
        __syncthreads();
        tmp[tid] += u;
        __syncthreads();
    }
    if (tid < nb) blk[tid] = tmp[tid] - v;  // exclusive prefix
}

// also fills cursor[] = start offsets so scatter needs no second memset
__global__ void scan_add_kernel(int* __restrict__ row_ptr, const int* __restrict__ blk,
                                int* __restrict__ cursor, int n) {
    int i = blockIdx.x * 256 + threadIdx.x;
    if (i < n) {
        int v = row_ptr[i + 1] + blk[blockIdx.x];
        row_ptr[i + 1] = v;
        cursor[i + 1] = v;
    }
    if (i == 0) { row_ptr[0] = 0; cursor[0] = 0; }
}

__global__ void scatter_kernel(const int* __restrict__ src, const int* __restrict__ dst,
                               int* __restrict__ cursor, int* __restrict__ csr_src, int e) {
    int i = blockIdx.x * 256 + threadIdx.x;
    if (i < e) {
        int dd = dst[i];
        int pos = atomicAdd(&cursor[dd], 1);
        csr_src[pos] = src[i];
    }
}

// ---------------- fused conv layer ----------------
// Block = 1024 threads = 16 waves = 16 nodes.
// Phase A: wave per node. Softmax-aggregation (shift-invariant, no max pass;
//   |t*x| <= ~8 so fp32 exp safe). 16-deep explicit gather ILP with clamped
//   indices + masked tail. Writes combined row A[node][k] = [aggr | x] to LDS.
// Phase B: cooperative matmul. Wave w: k-quarter (w&3) x 4 nodes ((w>>2)*4..+3);
//   each weight float4 read once per 4 nodes (8 KB/node LDS traffic vs 32 KB).
//   Partials reduced in LDS, then instnorm + ReLU + store + atomicMax readout.

template <int C_IN>
__global__ void __launch_bounds__(1024, 8) conv_kernel(
        const float* __restrict__ xin, const float* __restrict__ tptr,
        const int* __restrict__ row_ptr, const int* __restrict__ csr_src,
        const int* __restrict__ batch,
        const float* __restrict__ Wr, const float* __restrict__ br,
        const float* __restrict__ Ws,
        float* __restrict__ yout, float* __restrict__ hmax, int n) {
    constexpr int K_TOT = (C_IN == 64) ? 128 : 64;   // combined [aggr|x] row length
    constexpr int K4    = K_TOT / 4;
    constexpr int QK4   = K4 / 4;

    __shared__ float wLDS[K4 * 256];        // [k4][lane][4] : W[k][l], conflict-free b128
    __shared__ float aLDS[16 * K_TOT];      // A[node][k]
    __shared__ float part[4][16][64];       // [quarter][node][lane]

    int tid = threadIdx.x;
    int w = tid >> 6, l = tid & 63;

    // ---- stage combined transposed weights (one-time) ----
    if (C_IN == 64) {
        for (int idx = tid; idx < 64 * 128; idx += 1024) {
            int k = idx & 127, ll = idx >> 7;
            float val = (k < 64) ? Wr[ll * 64 + k] : Ws[ll * 64 + (k - 64)];
            wLDS[(k >> 2) * 256 + ll * 4 + (k & 3)] = val;
        }
    } else {
        for (int idx = tid; idx < 64 * 64; idx += 1024) {
            int k = idx & 63, ll = idx >> 6;
            float val = (k < C_IN) ? Wr[ll * C_IN + k]
                      : (k < 2 * C_IN) ? Ws[ll * C_IN + (k - C_IN)] : 0.f;
            wLDS[(k >> 2) * 256 + ll * 4 + (k & 3)] = val;
        }
    }

    // ---- Phase A: aggregation, one wave per node ----
    int d = blockIdx.x * 16 + w;
    float tval = tptr[0];
    int loff = (l < C_IN) ? l : 0;
    if (d < n) {
        float xr = xin[d * C_IN + loff];
        int beg = row_ptr[d], end = row_ptr[d + 1];
        float den = 0.f, num = 0.f;
        for (int base = beg; base < end; base += 64) {
            int cnt = end - base;
            if (cnt > 64) cnt = 64;
            int sidx = csr_src[base + ((l < cnt) ? l : (cnt - 1))];  // coalesced
            for (int j = 0; j < cnt; j += 16) {
                float v[16];
                #pragma unroll
                for (int i = 0; i < 16; ++i) {
                    int jj = j + i;
                    if (jj >= cnt) jj = cnt - 1;                     // uniform clamp
                    int s = __builtin_amdgcn_readlane(sidx, jj);
                    v[i] = xin[s * C_IN + loff];
                }
                #pragma unroll
                for (int i = 0; i < 16; ++i) {
                    float e = ((j + i) < cnt) ? __expf(tval * v[i]) : 0.f;
                    den += e;
                    num = fmaf(v[i], e, num);
                }
            }
        }
        float aggr = (end > beg) ? num / den : 0.f;
        if (C_IN == 64) {
            aLDS[w * 128 + l] = aggr;
            aLDS[w * 128 + 64 + l] = xr;
        } else {
            float xs = __shfl(xr, (l - C_IN) & 63);   // lane l gets x-chan (l-31)
            float av = (l < C_IN) ? aggr : ((l < 2 * C_IN) ? xs : 0.f);
            aLDS[w * 64 + l] = av;
        }
    } else {
        // keep A rows defined (avoid NaN garbage feeding Phase B)
        if (C_IN == 64) { aLDS[w * 128 + l] = 0.f; aLDS[w * 128 + 64 + l] = 0.f; }
        else             { aLDS[w * 64 + l] = 0.f; }
    }
    __syncthreads();

    // ---- Phase B: cooperative matmul, weights amortized over 4 nodes ----
    {
        int q = w & 3;
        int n0 = (w >> 2) * 4;
        float acc0 = 0.f, acc1 = 0.f, acc2 = 0.f, acc3 = 0.f;
        #pragma unroll
        for (int kk = 0; kk < QK4; ++kk) {
            int k4 = q * QK4 + kk;
            float4 w4 = *(const float4*)&wLDS[k4 * 256 + l * 4];
            float4 a0 = *(const float4*)&aLDS[(n0 + 0) * K_TOT + k4 * 4];
            float4 a1 = *(const float4*)&aLDS[(n0 + 1) * K_TOT + k4 * 4];
            float4 a2 = *(const float4*)&aLDS[(n0 + 2) * K_TOT + k4 * 4];
            float4 a3 = *(const float4*)&aLDS[(n0 + 3) * K_TOT + k4 * 4];
            acc0 = fmaf(a0.x, w4.x, acc0); acc0 = fmaf(a0.y, w4.y, acc0);
            acc0 = fmaf(a0.z, w4.z, acc0); acc0 = fmaf(a0.w, w4.w, acc0);
            acc1 = fmaf(a1.x, w4.x, acc1); acc1 = fmaf(a1.y, w4.y, acc1);
            acc1 = fmaf(a1.z, w4.z, acc1); acc1 = fmaf(a1.w, w4.w, acc1);
            acc2 = fmaf(a2.x, w4.x, acc2); acc2 = fmaf(a2.y, w4.y, acc2);
            acc2 = fmaf(a2.z, w4.z, acc2); acc2 = fmaf(a2.w, w4.w, acc2);
            acc3 = fmaf(a3.x, w4.x, acc3); acc3 = fmaf(a3.y, w4.y, acc3);
            acc3 = fmaf(a3.z, w4.z, acc3); acc3 = fmaf(a3.w, w4.w, acc3);
        }
        part[q][n0 + 0][l] = acc0;
        part[q][n0 + 1][l] = acc1;
        part[q][n0 + 2][l] = acc2;
        part[q][n0 + 3][l] = acc3;
    }
    __syncthreads();

    // ---- reduce + instance norm + ReLU + store + graph-max (wave w -> node w) ----
    if (d < n) {
        float acc = part[0][w][l] + part[1][w][l] + part[2][w][l] + part[3][w][l] + br[l];
        float s = acc;
        for (int off = 32; off > 0; off >>= 1) s += __shfl_xor(s, off);
        float mu = s * (1.0f / 64.0f);
        float dc = acc - mu;
        float s2 = dc * dc;
        for (int off = 32; off > 0; off >>= 1) s2 += __shfl_xor(s2, off);
        float var = s2 * (1.0f / 64.0f);
        float y = dc * rsqrtf(var + 1e-5f);
        y = fmaxf(y, 0.f);
        yout[d * 64 + l] = y;
        int g = batch[d];
        // y >= 0 and hmax zero-initialized: int-punned atomicMax is order-correct
        atomicMax((int*)&hmax[g * 64 + l], __float_as_int(y));
    }
}

// ---------------- MLP head ----------------

__global__ void mlp_kernel(const float* __restrict__ h,  // [3][G][64]
                           const float* __restrict__ Wl1, const float* __restrict__ bl1,
                           const float* __restrict__ Wl2, const float* __restrict__ bl2,
                           float* __restrict__ out) {
    __shared__ float hrow[192];
    __shared__ float z1[128];
    __shared__ float z2[32];
    __shared__ float snorm;
    int g = blockIdx.x, tid = threadIdx.x;  // 128 threads
    if (tid < 64) {
        hrow[tid]       = h[0 * N_GRAPHS * 64 + g * 64 + tid];
        hrow[64 + tid]  = h[1 * N_GRAPHS * 64 + g * 64 + tid];
        hrow[128 + tid] = h[2 * N_GRAPHS * 64 + g * 64 + tid];
    }
    __syncthreads();
    float acc = bl1[tid];
    #pragma unroll 8
    for (int c = 0; c < 192; ++c) acc = fmaf(hrow[c], Wl1[tid * 192 + c], acc);
    z1[tid] = fmaxf(acc, 0.f);
    __syncthreads();
    if (tid < 32) {
        float a2 = bl2[tid];
        #pragma unroll 8
        for (int c = 0; c < 128; ++c) a2 = fmaf(z1[c], Wl2[tid * 128 + c], a2);
        z2[tid] = a2;
    }
    __syncthreads();
    if (tid == 0) {
        float ss = 0.f;
        for (int i = 0; i < 32; ++i) ss += z2[i] * z2[i];
        snorm = fmaxf(sqrtf(ss), 1e-12f);
    }
    __syncthreads();
    if (tid < 32) out[g * 32 + tid] = z2[tid] / snorm;
}

// ---------------- launch ----------------

extern "C" void kernel_launch(void* const* d_in, const int* in_sizes, int n_in,
                              void* d_out, int out_size, void* d_ws, size_t ws_size,
                              hipStream_t stream) {
    const float* x   = (const float*)d_in[0];
    const int* eidx  = (const int*)d_in[1];
    const int* batch = (const int*)d_in[2];
    const float* t   = (const float*)d_in[3];
    const float* W1r = (const float*)d_in[4];
    const float* b1  = (const float*)d_in[5];
    const float* W1s = (const float*)d_in[6];
    const float* W2r = (const float*)d_in[7];
    const float* b2  = (const float*)d_in[8];
    const float* W2s = (const float*)d_in[9];
    const float* W3r = (const float*)d_in[10];
    const float* b3  = (const float*)d_in[11];
    const float* W3s = (const float*)d_in[12];
    const float* Wl1 = (const float*)d_in[13];
    const float* bl1 = (const float*)d_in[14];
    const float* Wl2 = (const float*)d_in[15];
    const float* bl2 = (const float*)d_in[16];
    float* out = (float*)d_out;

    const int nE = in_sizes[1] / 2;
    const int nN = in_sizes[2];
    const int* src = eidx;
    const int* dst = eidx + nE;

    char* ws = (char*)d_ws;
    size_t off = 0;
    auto alloc = [&](size_t bytes) {
        char* p = ws + off;
        off = (off + bytes + 255) & ~(size_t)255;
        return p;
    };
    int*   counts  = (int*)alloc((size_t)nN * 4);
    int*   row_ptr = (int*)alloc((size_t)(nN + 1) * 4);
    int*   cursor  = (int*)alloc((size_t)(nN + 1) * 4);
    int*   blk     = (int*)alloc(256 * 4);
    int*   csr_src = (int*)alloc((size_t)nE * 4);
    float* yA      = (float*)alloc((size_t)nN * 64 * 4);
    float* yB      = (float*)alloc((size_t)nN * 64 * 4);
    float* h       = (float*)alloc((size_t)3 * N_GRAPHS * 64 * 4);

    const int nbE = (nE + 255) / 256;
    const int nbN = (nN + 255) / 256;

    hipMemsetAsync(counts, 0, (size_t)nN * 4, stream);
    hist_kernel<<<nbE, 256, 0, stream>>>(dst, counts, nE);
    scan_blocks_kernel<<<nbN, 256, 0, stream>>>(counts, row_ptr, blk, nN);
    scan_partials_kernel<<<1, 256, 0, stream>>>(blk, nbN);
    scan_add_kernel<<<nbN, 256, 0, stream>>>(row_ptr, blk, cursor, nN);
    scatter_kernel<<<nbE, 256, 0, stream>>>(src, dst, cursor, csr_src, nE);
    hipMemsetAsync(h, 0, (size_t)3 * N_GRAPHS * 64 * 4, stream);

    const int nbC = (nN + 15) / 16;
    conv_kernel<IN_CH><<<nbC, 1024, 0, stream>>>(x, t, row_ptr, csr_src, batch,
                                                 W1r, b1, W1s, yA, h + 0 * N_GRAPHS * 64, nN);
    conv_kernel<HID><<<nbC, 1024, 0, stream>>>(yA, t, row_ptr, csr_src, batch,
                                               W2r, b2, W2s, yB, h + 1 * N_GRAPHS * 64, nN);
    conv_kernel<HID><<<nbC, 1024, 0, stream>>>(yB, t, row_ptr, csr_src, batch,
                                               W3r, b3, W3s, yA, h + 2 * N_GRAPHS * 64, nN);
    mlp_kernel<<<N_GRAPHS, 128, 0, stream>>>(h, Wl1, bl1, Wl2, bl2, out);
}

// Round 5
// 429.497 us; speedup vs baseline: 2.1832x; 1.0013x over previous
//
#include <hip/hip_runtime.h>

#define N_NODES 50000
#define N_EDGES 800000
#define N_GRAPHS 128
#define IN_CH 31
#define HID 64

// ---------------- CSR build ----------------

__global__ void hist_kernel(const int* __restrict__ dst, int* __restrict__ counts, int e) {
    int i = blockIdx.x * 256 + threadIdx.x;
    int i4 = i * 4;
    if (i4 + 4 <= e) {
        int4 d4 = *(const int4*)(dst + i4);
        atomicAdd(&counts[d4.x], 1);
        atomicAdd(&counts[d4.y], 1);
        atomicAdd(&counts[d4.z], 1);
        atomicAdd(&counts[d4.w], 1);
    } else {
        for (int j = i4; j < e; ++j) atomicAdd(&counts[dst[j]], 1);
    }
}

__global__ void scan_blocks_kernel(const int* __restrict__ counts, int* __restrict__ row_ptr,
                                   int* __restrict__ blk, int n) {
    __shared__ int tmp[256];
    int tid = threadIdx.x;
    int i = blockIdx.x * 256 + tid;
    int v = (i < n) ? counts[i] : 0;
    tmp[tid] = v;
    __syncthreads();
    for (int off = 1; off < 256; off <<= 1) {
        int u = (tid >= off) ? tmp[tid - off] : 0;
        __syncthreads();
        tmp[tid] += u;
        __syncthreads();
    }
    if (i < n) row_ptr[i + 1] = tmp[tid];
    if (tid == 255) blk[blockIdx.x] = tmp[255];
}

__global__ void scan_partials_kernel(int* __restrict__ blk, int nb) {
    __shared__ int tmp[256];
    int tid = threadIdx.x;
    int v = (tid < nb) ? blk[tid] : 0;
    tmp[tid] = v;
    __syncthreads();
    for (int off = 1; off < 256; off <<= 1) {
        int u = (tid >= off) ? tmp[tid - off] : 0;
        __syncthreads();
        tmp[tid] += u;
        __syncthreads();
    }
    if (tid < nb) blk[tid] = tmp[tid] - v;  // exclusive prefix
}

// also fills cursor[] = start offsets so scatter needs no second memset
__global__ void scan_add_kernel(int* __restrict__ row_ptr, const int* __restrict__ blk,
                                int* __restrict__ cursor, int n) {
    int i = blockIdx.x * 256 + threadIdx.x;
    if (i < n) {
        int v = row_ptr[i + 1] + blk[blockIdx.x];
        row_ptr[i + 1] = v;
        cursor[i + 1] = v;
    }
    if (i == 0) { row_ptr[0] = 0; cursor[0] = 0; }
}

__global__ void scatter_kernel(const int* __restrict__ src, const int* __restrict__ dst,
                               int* __restrict__ cursor, int* __restrict__ csr_src, int e) {
    int i = blockIdx.x * 256 + threadIdx.x;
    int i4 = i * 4;
    if (i4 + 4 <= e) {
        int4 s4 = *(const int4*)(src + i4);
        int4 d4 = *(const int4*)(dst + i4);
        csr_src[atomicAdd(&cursor[d4.x], 1)] = s4.x;
        csr_src[atomicAdd(&cursor[d4.y], 1)] = s4.y;
        csr_src[atomicAdd(&cursor[d4.z], 1)] = s4.z;
        csr_src[atomicAdd(&cursor[d4.w], 1)] = s4.w;
    } else {
        for (int j = i4; j < e; ++j) csr_src[atomicAdd(&cursor[dst[j]], 1)] = src[j];
    }
}

// ---------------- fused conv layer ----------------
// Block = 1024 threads = 16 waves = 16 nodes.
// Phase A: wave per node. Softmax-aggregation (shift-invariant, no max pass;
//   |t*x| <= ~8 so fp32 exp safe). ALL loop control scalarized via
//   readfirstlane(row_ptr) so readlane takes SGPR indices and the 16 gathers
//   per batch issue back-to-back (true 16-deep MLP). Tail batch masked with a
//   wave-uniform multiplicative mask.
// Phase B: cooperative matmul. Wave w: k-quarter (w&3) x 4 nodes; each weight
//   float4 read once per 4 nodes. Staging writes are destination-ordered
//   (consecutive tid -> consecutive LDS addr -> conflict-free).

template <int C_IN>
__global__ void __launch_bounds__(1024, 8) conv_kernel(
        const float* __restrict__ xin, const float* __restrict__ tptr,
        const int* __restrict__ row_ptr, const int* __restrict__ csr_src,
        const int* __restrict__ batch,
        const float* __restrict__ Wr, const float* __restrict__ br,
        const float* __restrict__ Ws,
        float* __restrict__ yout, float* __restrict__ hmax, int n) {
    constexpr int K_TOT = (C_IN == 64) ? 128 : 64;   // combined [aggr|x] row length
    constexpr int K4    = K_TOT / 4;
    constexpr int QK4   = K4 / 4;

    __shared__ float wLDS[K4 * 256];        // [k4][lane][4] : W[k][l]
    __shared__ float aLDS[16 * K_TOT];      // A[node][k]
    __shared__ float part[4][16][64];       // [quarter][node][lane]

    int tid = threadIdx.x;
    int w = tid >> 6, l = tid & 63;

    // ---- stage combined transposed weights, destination-ordered ----
    for (int idx = tid; idx < K4 * 256; idx += 1024) {
        int k4 = idx >> 8;
        int ll = (idx >> 2) & 63;
        int i  = idx & 3;
        int k  = k4 * 4 + i;
        float val;
        if (C_IN == 64) {
            val = (k < 64) ? Wr[ll * 64 + k] : Ws[ll * 64 + (k - 64)];
        } else {
            val = (k < C_IN) ? Wr[ll * C_IN + k]
                : (k < 2 * C_IN) ? Ws[ll * C_IN + (k - C_IN)] : 0.f;
        }
        wLDS[idx] = val;
    }

    // ---- Phase A: aggregation, one wave per node ----
    int d = blockIdx.x * 16 + w;
    float tval = tptr[0];
    int loff = (l < C_IN) ? l : 0;
    if (d < n) {
        float xr = xin[d * C_IN + loff];
        int beg = __builtin_amdgcn_readfirstlane(row_ptr[d]);
        int end = __builtin_amdgcn_readfirstlane(row_ptr[d + 1]);
        float den = 0.f, num = 0.f;
        int base = beg;
        // full 64-edge batches (rare: avg degree 16)
        for (; base + 64 <= end; base += 64) {
            int sidx = csr_src[base + l];
            #pragma unroll
            for (int j = 0; j < 64; j += 16) {
                float v[16];
                #pragma unroll
                for (int i = 0; i < 16; ++i) {
                    int s = __builtin_amdgcn_readlane(sidx, j + i);
                    v[i] = xin[s * C_IN + loff];
                }
                #pragma unroll
                for (int i = 0; i < 16; ++i) {
                    float e = __expf(tval * v[i]);
                    den += e;
                    num = fmaf(v[i], e, num);
                }
            }
        }
        int rem = end - base;                      // scalar, 0..63
        if (rem > 0) {
            int sidx = csr_src[base + ((l < rem) ? l : 0)];
            for (int j = 0; j < rem; j += 16) {    // scalar loop, usually 1 iter
                float v[16];
                #pragma unroll
                for (int i = 0; i < 16; ++i) {
                    int jj = j + i;
                    if (jj >= rem) jj = rem - 1;   // scalar clamp (safe dup)
                    int s = __builtin_amdgcn_readlane(sidx, jj);
                    v[i] = xin[s * C_IN + loff];
                }
                #pragma unroll
                for (int i = 0; i < 16; ++i) {
                    float m = (j + i < rem) ? 1.f : 0.f;   // wave-uniform mask
                    float e = __expf(tval * v[i]) * m;
                    den += e;
                    num = fmaf(v[i], e, num);
                }
            }
        }
        float aggr = (end > beg) ? num / den : 0.f;
        if (C_IN == 64) {
            aLDS[w * 128 + l] = aggr;
            aLDS[w * 128 + 64 + l] = xr;
        } else {
            float xs = __shfl(xr, (l - C_IN) & 63);   // lane l gets x-chan (l-31)
            float av = (l < C_IN) ? aggr : ((l < 2 * C_IN) ? xs : 0.f);
            aLDS[w * 64 + l] = av;
        }
    } else {
        if (C_IN == 64) { aLDS[w * 128 + l] = 0.f; aLDS[w * 128 + 64 + l] = 0.f; }
        else             { aLDS[w * 64 + l] = 0.f; }
    }
    __syncthreads();

    // ---- Phase B: cooperative matmul, weights amortized over 4 nodes ----
    {
        int q = w & 3;
        int n0 = (w >> 2) * 4;
        float acc0 = 0.f, acc1 = 0.f, acc2 = 0.f, acc3 = 0.f;
        #pragma unroll
        for (int kk = 0; kk < QK4; ++kk) {
            int k4 = q * QK4 + kk;
            float4 w4 = *(const float4*)&wLDS[k4 * 256 + l * 4];
            float4 a0 = *(const float4*)&aLDS[(n0 + 0) * K_TOT + k4 * 4];
            float4 a1 = *(const float4*)&aLDS[(n0 + 1) * K_TOT + k4 * 4];
            float4 a2 = *(const float4*)&aLDS[(n0 + 2) * K_TOT + k4 * 4];
            float4 a3 = *(const float4*)&aLDS[(n0 + 3) * K_TOT + k4 * 4];
            acc0 = fmaf(a0.x, w4.x, acc0); acc0 = fmaf(a0.y, w4.y, acc0);
            acc0 = fmaf(a0.z, w4.z, acc0); acc0 = fmaf(a0.w, w4.w, acc0);
            acc1 = fmaf(a1.x, w4.x, acc1); acc1 = fmaf(a1.y, w4.y, acc1);
            acc1 = fmaf(a1.z, w4.z, acc1); acc1 = fmaf(a1.w, w4.w, acc1);
            acc2 = fmaf(a2.x, w4.x, acc2); acc2 = fmaf(a2.y, w4.y, acc2);
            acc2 = fmaf(a2.z, w4.z, acc2); acc2 = fmaf(a2.w, w4.w, acc2);
            acc3 = fmaf(a3.x, w4.x, acc3); acc3 = fmaf(a3.y, w4.y, acc3);
            acc3 = fmaf(a3.z, w4.z, acc3); acc3 = fmaf(a3.w, w4.w, acc3);
        }
        part[q][n0 + 0][l] = acc0;
        part[q][n0 + 1][l] = acc1;
        part[q][n0 + 2][l] = acc2;
        part[q][n0 + 3][l] = acc3;
    }
    __syncthreads();

    // ---- reduce + instance norm + ReLU + store + graph-max (wave w -> node w) ----
    if (d < n) {
        float acc = part[0][w][l] + part[1][w][l] + part[2][w][l] + part[3][w][l] + br[l];
        float s = acc;
        for (int off = 32; off > 0; off >>= 1) s += __shfl_xor(s, off);
        float mu = s * (1.0f / 64.0f);
        float dc = acc - mu;
        float s2 = dc * dc;
        for (int off = 32; off > 0; off >>= 1) s2 += __shfl_xor(s2, off);
        float var = s2 * (1.0f / 64.0f);
        float y = dc * rsqrtf(var + 1e-5f);
        y = fmaxf(y, 0.f);
        yout[d * 64 + l] = y;
        int g = batch[d];
        // y >= 0 and hmax zero-initialized: int-punned atomicMax is order-correct
        atomicMax((int*)&hmax[g * 64 + l], __float_as_int(y));
    }
}

// ---------------- MLP head ----------------

__global__ void mlp_kernel(const float* __restrict__ h,  // [3][G][64]
                           const float* __restrict__ Wl1, const float* __restrict__ bl1,
                           const float* __restrict__ Wl2, const float* __restrict__ bl2,
                           float* __restrict__ out) {
    __shared__ float hrow[192];
    __shared__ float z1[128];
    __shared__ float z2[32];
    __shared__ float snorm;
    int g = blockIdx.x, tid = threadIdx.x;  // 128 threads
    if (tid < 64) {
        hrow[tid]       = h[0 * N_GRAPHS * 64 + g * 64 + tid];
        hrow[64 + tid]  = h[1 * N_GRAPHS * 64 + g * 64 + tid];
        hrow[128 + tid] = h[2 * N_GRAPHS * 64 + g * 64 + tid];
    }
    __syncthreads();
    float acc = bl1[tid];
    #pragma unroll 8
    for (int c = 0; c < 192; ++c) acc = fmaf(hrow[c], Wl1[tid * 192 + c], acc);
    z1[tid] = fmaxf(acc, 0.f);
    __syncthreads();
    if (tid < 32) {
        float a2 = bl2[tid];
        #pragma unroll 8
        for (int c = 0; c < 128; ++c) a2 = fmaf(z1[c], Wl2[tid * 128 + c], a2);
        z2[tid] = a2;
    }
    __syncthreads();
    if (tid == 0) {
        float ss = 0.f;
        for (int i = 0; i < 32; ++i) ss += z2[i] * z2[i];
        snorm = fmaxf(sqrtf(ss), 1e-12f);
    }
    __syncthreads();
    if (tid < 32) out[g * 32 + tid] = z2[tid] / snorm;
}

// ---------------- launch ----------------

extern "C" void kernel_launch(void* const* d_in, const int* in_sizes, int n_in,
                              void* d_out, int out_size, void* d_ws, size_t ws_size,
                              hipStream_t stream) {
    const float* x   = (const float*)d_in[0];
    const int* eidx  = (const int*)d_in[1];
    const int* batch = (const int*)d_in[2];
    const float* t   = (const float*)d_in[3];
    const float* W1r = (const float*)d_in[4];
    const float* b1  = (const float*)d_in[5];
    const float* W1s = (const float*)d_in[6];
    const float* W2r = (const float*)d_in[7];
    const float* b2  = (const float*)d_in[8];
    const float* W2s = (const float*)d_in[9];
    const float* W3r = (const float*)d_in[10];
    const float* b3  = (const float*)d_in[11];
    const float* W3s = (const float*)d_in[12];
    const float* Wl1 = (const float*)d_in[13];
    const float* bl1 = (const float*)d_in[14];
    const float* Wl2 = (const float*)d_in[15];
    const float* bl2 = (const float*)d_in[16];
    float* out = (float*)d_out;

    const int nE = in_sizes[1] / 2;
    const int nN = in_sizes[2];
    const int* src = eidx;
    const int* dst = eidx + nE;

    char* ws = (char*)d_ws;
    size_t off = 0;
    auto alloc = [&](size_t bytes) {
        char* p = ws + off;
        off = (off + bytes + 255) & ~(size_t)255;
        return p;
    };
    int*   counts  = (int*)alloc((size_t)nN * 4);
    int*   row_ptr = (int*)alloc((size_t)(nN + 1) * 4);
    int*   cursor  = (int*)alloc((size_t)(nN + 1) * 4);
    int*   blk     = (int*)alloc(256 * 4);
    int*   csr_src = (int*)alloc((size_t)nE * 4);
    float* yA      = (float*)alloc((size_t)nN * 64 * 4);
    float* yB      = (float*)alloc((size_t)nN * 64 * 4);
    float* h       = (float*)alloc((size_t)3 * N_GRAPHS * 64 * 4);

    const int nbE4 = (nE / 4 + 255) / 256 + 1;
    const int nbN  = (nN + 255) / 256;

    hipMemsetAsync(counts, 0, (size_t)nN * 4, stream);
    hist_kernel<<<nbE4, 256, 0, stream>>>(dst, counts, nE);
    scan_blocks_kernel<<<nbN, 256, 0, stream>>>(counts, row_ptr, blk, nN);
    scan_partials_kernel<<<1, 256, 0, stream>>>(blk, nbN);
    scan_add_kernel<<<nbN, 256, 0, stream>>>(row_ptr, blk, cursor, nN);
    scatter_kernel<<<nbE4, 256, 0, stream>>>(src, dst, cursor, csr_src, nE);
    hipMemsetAsync(h, 0, (size_t)3 * N_GRAPHS * 64 * 4, stream);

    const int nbC = (nN + 15) / 16;
    conv_kernel<IN_CH><<<nbC, 1024, 0, stream>>>(x, t, row_ptr, csr_src, batch,
                                                 W1r, b1, W1s, yA, h + 0 * N_GRAPHS * 64, nN);
    conv_kernel<HID><<<nbC, 1024, 0, stream>>>(yA, t, row_ptr, csr_src, batch,
                                               W2r, b2, W2s, yB, h + 1 * N_GRAPHS * 64, nN);
    conv_kernel<HID><<<nbC, 1024, 0, stream>>>(yB, t, row_ptr, csr_src, batch,
                                               W3r, b3, W3s, yA, h + 2 * N_GRAPHS * 64, nN);
    mlp_kernel<<<N_GRAPHS, 128, 0, stream>>>(h, Wl1, bl1, Wl2, bl2, out);
}